// Round 1
// baseline (172.555 us; speedup 1.0000x reference)
//
#include <hip/hip_runtime.h>
#include <math.h>

// Problem: B=8, H=32, W=32, C=512  ->  HW=1024, rows = B*HW = 8192
// Algebraic collapse: rep[b,i] = pos_coeff * (x[b,i]·u_b + const_b); min-max norm
// kills pos_coeff and const_b, so we only need u_b (8 x 512) and two passes over x.

#define BATCH 8
#define HW    1024
#define CH    512
#define SPLITS 64
#define ROWS_PER_BLOCK (HW / SPLITS)   // 16

// -------------------- pass A: partial per-batch channel sums of x --------------------
__global__ void k_xsum_part(const float* __restrict__ x, float* __restrict__ part) {
    int s = blockIdx.x, b = blockIdx.y, t = threadIdx.x;          // 256 threads, float2 each
    const float2* xbase = (const float2*)(x + ((size_t)(b * HW + s * ROWS_PER_BLOCK)) * CH);
    float2 acc; acc.x = 0.f; acc.y = 0.f;
    #pragma unroll
    for (int r = 0; r < ROWS_PER_BLOCK; ++r) {
        float2 v = xbase[r * (CH / 2) + t];
        acc.x += v.x; acc.y += v.y;
    }
    ((float2*)(part + ((size_t)(b * SPLITS + s)) * CH))[t] = acc;
}

// -------------------- pass B: reduce partials -> xsum[8][512] --------------------
__global__ void k_xsum_red(const float* __restrict__ part, float* __restrict__ xsum) {
    int b = blockIdx.x, t = threadIdx.x;
    const float2* pb = (const float2*)(part + (size_t)b * SPLITS * CH);
    float2 acc; acc.x = 0.f; acc.y = 0.f;
    #pragma unroll 8
    for (int s = 0; s < SPLITS; ++s) {
        float2 v = pb[s * (CH / 2) + t];
        acc.x += v.x; acc.y += v.y;
    }
    ((float2*)(xsum + b * CH))[t] = acc;
}

// -------------------- xrsum[b][o] = xsum[b]·conv_w[o] + 1024*conv_b[o] + xsum[b][o] ----
__global__ void k_xrsum(const float* __restrict__ xsum, const float* __restrict__ conv_w,
                        const float* __restrict__ conv_b, float* __restrict__ xrsum) {
    int g = blockIdx.x * blockDim.x + threadIdx.x;   // 4096 outputs
    int b = g >> 9, o = g & 511;
    const float4* xs4 = (const float4*)(xsum + b * CH);
    const float4* w4  = (const float4*)(conv_w + o * CH);
    float acc0 = 0.f, acc1 = 0.f;
    #pragma unroll 4
    for (int j = 0; j < CH / 8; ++j) {
        float4 a = xs4[2 * j],     w = w4[2 * j];
        float4 a2 = xs4[2 * j + 1], w2 = w4[2 * j + 1];
        acc0 += a.x * w.x + a.y * w.y + a.z * w.z + a.w * w.w;
        acc1 += a2.x * w2.x + a2.y * w2.y + a2.z * w2.z + a2.w * w2.w;
    }
    xrsum[g] = acc0 + acc1 + 1024.f * conv_b[o] + xsum[b * CH + o];
}

// -------------------- ksum[b][o] = xrsum[b]·k_w[o] + 1024*k_b[o] --------------------
__global__ void k_ksum(const float* __restrict__ xrsum, const float* __restrict__ k_w,
                       const float* __restrict__ k_b, float* __restrict__ ksum) {
    int g = blockIdx.x * blockDim.x + threadIdx.x;
    int b = g >> 9, o = g & 511;
    const float4* xs4 = (const float4*)(xrsum + b * CH);
    const float4* w4  = (const float4*)(k_w + o * CH);
    float acc0 = 0.f, acc1 = 0.f;
    #pragma unroll 4
    for (int j = 0; j < CH / 8; ++j) {
        float4 a = xs4[2 * j],      w = w4[2 * j];
        float4 a2 = xs4[2 * j + 1], w2 = w4[2 * j + 1];
        acc0 += a.x * w.x + a.y * w.y + a.z * w.z + a.w * w.w;
        acc1 += a2.x * w2.x + a2.y * w2.y + a2.z * w2.z + a2.w * w2.w;
    }
    ksum[g] = acc0 + acc1 + 1024.f * k_b[o];
}

// ------ wvec[b][c] = sum_o q_w[o][c] * (Ktot[o] - ksum[b][o]) ------
__global__ void k_wvec(const float* __restrict__ ksum, const float* __restrict__ q_w,
                       float* __restrict__ wvec) {
    int g = blockIdx.x * blockDim.x + threadIdx.x;
    int b = g >> 9, c = g & 511;                     // b uniform per block (256 thr)
    __shared__ float vsh[CH];
    for (int o = threadIdx.x; o < CH; o += blockDim.x) {
        float kt = 0.f;
        #pragma unroll
        for (int bb = 0; bb < BATCH; ++bb) kt += ksum[bb * CH + o];
        vsh[o] = kt - ksum[b * CH + o];
    }
    __syncthreads();
    float acc = 0.f;
    #pragma unroll 8
    for (int o = 0; o < CH; ++o) acc += q_w[o * CH + c] * vsh[o];
    wvec[g] = acc;
}

// ------ uvec[b][c] = sum_o conv_w[o][c] * wvec[b][o] + wvec[b][c] ------
__global__ void k_uvec(const float* __restrict__ wvec, const float* __restrict__ conv_w,
                       float* __restrict__ uvec) {
    int g = blockIdx.x * blockDim.x + threadIdx.x;
    int b = g >> 9, c = g & 511;
    __shared__ float wsh[CH];
    for (int o = threadIdx.x; o < CH; o += blockDim.x) wsh[o] = wvec[b * CH + o];
    __syncthreads();
    float acc = 0.f;
    #pragma unroll 8
    for (int o = 0; o < CH; ++o) acc += conv_w[o * CH + c] * wsh[o];
    uvec[g] = acc + wsh[c];
}

// -------------------- pass G: d[b,p] = x[b,p]·u_b, plus per-block min/max ----------
__global__ void k_dpass(const float* __restrict__ x, const float* __restrict__ uvec,
                        float* __restrict__ dvals, float* __restrict__ bmin,
                        float* __restrict__ bmax) {
    int s = blockIdx.x, b = blockIdx.y;
    int lane = threadIdx.x & 63, wave = threadIdx.x >> 6;   // 4 waves
    const float4* u4 = (const float4*)(uvec + b * CH);
    float4 ua = u4[lane], ub = u4[lane + 64];               // u cached in regs
    __shared__ float sd[ROWS_PER_BLOCK];
    int p0 = s * ROWS_PER_BLOCK;
    #pragma unroll
    for (int it = 0; it < ROWS_PER_BLOCK / 4; ++it) {
        int row = p0 + it * 4 + wave;
        const float4* x4 = (const float4*)(x + ((size_t)(b * HW + row)) * CH);
        float4 xa = x4[lane], xb = x4[lane + 64];
        float acc = xa.x * ua.x + xa.y * ua.y + xa.z * ua.z + xa.w * ua.w
                  + xb.x * ub.x + xb.y * ub.y + xb.z * ub.z + xb.w * ub.w;
        #pragma unroll
        for (int off = 32; off > 0; off >>= 1) acc += __shfl_down(acc, off);
        if (lane == 0) {
            dvals[b * HW + row] = acc;
            sd[it * 4 + wave] = acc;
        }
    }
    __syncthreads();
    if (threadIdx.x == 0) {
        float mn = sd[0], mx = sd[0];
        #pragma unroll
        for (int i = 1; i < ROWS_PER_BLOCK; ++i) {
            mn = fminf(mn, sd[i]); mx = fmaxf(mx, sd[i]);
        }
        bmin[b * SPLITS + s] = mn;
        bmax[b * SPLITS + s] = mx;
    }
}

// -------------------- pass H: min-max normalize + sigmoid --------------------
__global__ void k_out(const float* __restrict__ dvals, const float* __restrict__ bmin,
                      const float* __restrict__ bmax, float* __restrict__ out) {
    int b = blockIdx.x, t = threadIdx.x;
    __shared__ float smn, smx;
    if (t < 64) {
        float mn = bmin[b * SPLITS + t];
        float mx = bmax[b * SPLITS + t];
        #pragma unroll
        for (int off = 32; off > 0; off >>= 1) {
            mn = fminf(mn, __shfl_down(mn, off));
            mx = fmaxf(mx, __shfl_down(mx, off));
        }
        if (t == 0) { smn = mn; smx = mx; }
    }
    __syncthreads();
    float rmin = smn, inv = 1.f / (smx - smn);
    for (int i = t; i < HW; i += blockDim.x) {
        float d = dvals[b * HW + i];
        float rn = (d - rmin) * inv;
        float z = (rn - 0.65f) * (1.f / 0.15f);
        out[b * HW + i] = 1.f / (1.f + expf(-z));
    }
}

extern "C" void kernel_launch(void* const* d_in, const int* in_sizes, int n_in,
                              void* d_out, int out_size, void* d_ws, size_t ws_size,
                              hipStream_t stream) {
    const float* x      = (const float*)d_in[0];
    const float* conv_w = (const float*)d_in[1];
    const float* conv_b = (const float*)d_in[2];
    // d_in[3] = q_w, d_in[4] = q_b (q_b adds a per-batch constant -> cancels in min-max norm)
    const float* q_w    = (const float*)d_in[3];
    const float* k_w    = (const float*)d_in[5];
    const float* k_b    = (const float*)d_in[6];
    float* out = (float*)d_out;

    float* ws    = (float*)d_ws;
    float* part  = ws;                       // 8*64*512 = 262144
    float* xsum  = part + BATCH * SPLITS * CH;   // 4096
    float* xrsum = xsum + BATCH * CH;            // 4096
    float* ksum  = xrsum + BATCH * CH;           // 4096
    float* wvec  = ksum + BATCH * CH;            // 4096
    float* uvec  = wvec + BATCH * CH;            // 4096
    float* dvals = uvec + BATCH * CH;            // 8192
    float* bmn   = dvals + BATCH * HW;           // 512
    float* bmx   = bmn + BATCH * SPLITS;         // 512

    hipLaunchKernelGGL(k_xsum_part, dim3(SPLITS, BATCH), dim3(256), 0, stream, x, part);
    hipLaunchKernelGGL(k_xsum_red,  dim3(BATCH),         dim3(256), 0, stream, part, xsum);
    hipLaunchKernelGGL(k_xrsum,     dim3(16),            dim3(256), 0, stream, xsum, conv_w, conv_b, xrsum);
    hipLaunchKernelGGL(k_ksum,      dim3(16),            dim3(256), 0, stream, xrsum, k_w, k_b, ksum);
    hipLaunchKernelGGL(k_wvec,      dim3(16),            dim3(256), 0, stream, ksum, q_w, wvec);
    hipLaunchKernelGGL(k_uvec,      dim3(16),            dim3(256), 0, stream, wvec, conv_w, uvec);
    hipLaunchKernelGGL(k_dpass,     dim3(SPLITS, BATCH), dim3(256), 0, stream, x, uvec, dvals, bmn, bmx);
    hipLaunchKernelGGL(k_out,       dim3(BATCH),         dim3(256), 0, stream, dvals, bmn, bmx, out);
}

// Round 2
// 104.975 us; speedup vs baseline: 1.6438x; 1.6438x over previous
//
#include <hip/hip_runtime.h>
#include <math.h>

// B=8, H=32, W=32, C=512 -> HW=1024. Algebraic collapse of the reference:
//   rep[b,i] = pos_const * (x[b,i]·u_b + const_b);  min-max norm kills both consts.
//   y_b  = xsumtot - xsum_b                     (xsum_b = sum_hw x[b])
//   t1_b = conv_w·y_b + y_b + 7168*conv_b       (= xrsumtot - xrsum_b)
//   t2_b = k_w·t1_b + 7168*k_b                  (= Ktot - ksum_b)
//   w_b  = q_w^T·t2_b
//   u_b  = conv_w^T·w_b + w_b
//   d[b,i] = x[b,i]·u_b  -> per-batch min-max -> sigmoid((.-0.65)/0.15)

#define BATCH 8
#define HW    1024
#define CH    512
#define SPLITS 64
#define ROWS_PER_BLOCK (HW / SPLITS)   // 16

// -------- K0: transpose q_w and conv_w (512x512 each), LDS 64x64 tiles --------
__global__ void k_transpose(const float* __restrict__ qw, const float* __restrict__ cw,
                            float* __restrict__ qwT, float* __restrict__ cwT) {
    __shared__ float tile[64][65];
    const float* in = blockIdx.y ? cw : qw;
    float* out      = blockIdx.y ? cwT : qwT;
    int r0 = (blockIdx.x >> 3) * 64, c0 = (blockIdx.x & 7) * 64;
    for (int i = threadIdx.x; i < 4096; i += 256) {
        int r = i >> 6, c = i & 63;
        tile[r][c] = in[(r0 + r) * 512 + c0 + c];
    }
    __syncthreads();
    for (int i = threadIdx.x; i < 4096; i += 256) {
        int r = i >> 6, c = i & 63;
        out[(c0 + r) * 512 + r0 + c] = tile[c][r];   // stride-65 LDS: conflict-free
    }
}

// -------- K1: partial per-batch channel sums of x (512 blocks) --------
__global__ void k_xsum_part(const float* __restrict__ x, float* __restrict__ part) {
    int s = blockIdx.x, b = blockIdx.y, t = threadIdx.x;
    const float2* xbase = (const float2*)(x + ((size_t)(b * HW + s * ROWS_PER_BLOCK)) * CH);
    float2 acc; acc.x = 0.f; acc.y = 0.f;
    #pragma unroll
    for (int r = 0; r < ROWS_PER_BLOCK; ++r) {
        float2 v = xbase[r * (CH / 2) + t];
        acc.x += v.x; acc.y += v.y;
    }
    ((float2*)(part + ((size_t)(b * SPLITS + s)) * CH))[t] = acc;
}

// -------- K2: reduce partials and form y[b] = xsumtot - xsum_b (64 blocks) --------
__global__ void k_ycompute(const float* __restrict__ part, float* __restrict__ y) {
    int chunk = blockIdx.x, b = blockIdx.y;      // chunk: 64-channel slice
    int bp = threadIdx.x & 7, cp = threadIdx.x >> 3;   // bp = which batch, cp = float2 idx
    const float2* p2 = (const float2*)part;
    int c2 = chunk * 32 + cp;
    float2 acc; acc.x = 0.f; acc.y = 0.f;
    #pragma unroll 8
    for (int s = 0; s < SPLITS; ++s) {
        float2 v = p2[(size_t)(bp * SPLITS + s) * 256 + c2];
        acc.x += v.x; acc.y += v.y;
    }
    __shared__ float2 sh[8][32];
    sh[bp][cp] = acc;
    __syncthreads();
    if (threadIdx.x < 32) {
        int c = threadIdx.x;
        float2 tot; tot.x = 0.f; tot.y = 0.f;
        #pragma unroll
        for (int j = 0; j < 8; ++j) { tot.x += sh[j][c].x; tot.y += sh[j][c].y; }
        float2 own = sh[b][c];
        float2 r; r.x = tot.x - own.x; r.y = tot.y - own.y;
        ((float2*)y)[b * 256 + chunk * 32 + c] = r;
    }
}

// -------- one-wave-per-output 512-dot helper --------
__device__ __forceinline__ float wave_dot512(const float* __restrict__ a,
                                             const float* __restrict__ w, int lane) {
    const float4* a4 = (const float4*)a;
    const float4* w4 = (const float4*)w;
    float4 a0 = a4[lane], a1 = a4[lane + 64];
    float4 w0 = w4[lane], w1 = w4[lane + 64];
    float acc = a0.x * w0.x + a0.y * w0.y + a0.z * w0.z + a0.w * w0.w
              + a1.x * w1.x + a1.y * w1.y + a1.z * w1.z + a1.w * w1.w;
    #pragma unroll
    for (int off = 32; off; off >>= 1) acc += __shfl_xor(acc, off);
    return acc;
}

// -------- K3: t1[b][o] = cw[o]·y_b + y_b[o] + 7168*cb[o]  (1024 blocks, 4 waves) ----
__global__ void k_t1(const float* __restrict__ y, const float* __restrict__ cw,
                     const float* __restrict__ cb, float* __restrict__ t1) {
    int g = (blockIdx.x << 2) + (threadIdx.x >> 6);
    int lane = threadIdx.x & 63;
    int b = g >> 9, o = g & 511;
    float acc = wave_dot512(y + b * CH, cw + o * CH, lane);
    if (lane == 0) t1[g] = acc + y[b * CH + o] + 7168.f * cb[o];
}

// -------- K4: t2[b][o] = kw[o]·t1_b + 7168*kb[o] --------
__global__ void k_t2(const float* __restrict__ t1, const float* __restrict__ kw,
                     const float* __restrict__ kb, float* __restrict__ t2) {
    int g = (blockIdx.x << 2) + (threadIdx.x >> 6);
    int lane = threadIdx.x & 63;
    int b = g >> 9, o = g & 511;
    float acc = wave_dot512(t1 + b * CH, kw + o * CH, lane);
    if (lane == 0) t2[g] = acc + 7168.f * kb[o];
}

// -------- K5: w[b][c] = qwT[c]·t2_b --------
__global__ void k_wv(const float* __restrict__ t2, const float* __restrict__ qwT,
                     float* __restrict__ w) {
    int g = (blockIdx.x << 2) + (threadIdx.x >> 6);
    int lane = threadIdx.x & 63;
    int b = g >> 9, c = g & 511;
    float acc = wave_dot512(t2 + b * CH, qwT + c * CH, lane);
    if (lane == 0) w[g] = acc;
}

// -------- K6: u[b][c] = cwT[c]·w_b + w[b][c] --------
__global__ void k_uv(const float* __restrict__ w, const float* __restrict__ cwT,
                     float* __restrict__ u) {
    int g = (blockIdx.x << 2) + (threadIdx.x >> 6);
    int lane = threadIdx.x & 63;
    int b = g >> 9, c = g & 511;
    float acc = wave_dot512(w + b * CH, cwT + c * CH, lane);
    if (lane == 0) u[g] = acc + w[b * CH + c];
}

// -------- K7: d[b,p] = x[b,p]·u_b + per-block min/max (512 blocks) --------
__global__ void k_dpass(const float* __restrict__ x, const float* __restrict__ u,
                        float* __restrict__ dvals, float* __restrict__ bmin,
                        float* __restrict__ bmax) {
    int s = blockIdx.x, b = blockIdx.y;
    int lane = threadIdx.x & 63, wave = threadIdx.x >> 6;
    const float4* u4 = (const float4*)(u + b * CH);
    float4 ua = u4[lane], ub = u4[lane + 64];
    __shared__ float sd[ROWS_PER_BLOCK];
    int p0 = s * ROWS_PER_BLOCK;
    #pragma unroll
    for (int it = 0; it < ROWS_PER_BLOCK / 4; ++it) {
        int row = p0 + it * 4 + wave;
        const float4* x4 = (const float4*)(x + ((size_t)(b * HW + row)) * CH);
        float4 xa = x4[lane], xb = x4[lane + 64];
        float acc = xa.x * ua.x + xa.y * ua.y + xa.z * ua.z + xa.w * ua.w
                  + xb.x * ub.x + xb.y * ub.y + xb.z * ub.z + xb.w * ub.w;
        #pragma unroll
        for (int off = 32; off > 0; off >>= 1) acc += __shfl_down(acc, off);
        if (lane == 0) {
            dvals[b * HW + row] = acc;
            sd[it * 4 + wave] = acc;
        }
    }
    __syncthreads();
    if (threadIdx.x == 0) {
        float mn = sd[0], mx = sd[0];
        #pragma unroll
        for (int i = 1; i < ROWS_PER_BLOCK; ++i) {
            mn = fminf(mn, sd[i]); mx = fmaxf(mx, sd[i]);
        }
        bmin[b * SPLITS + s] = mn;
        bmax[b * SPLITS + s] = mx;
    }
}

// -------- K8: min-max normalize + sigmoid --------
__global__ void k_out(const float* __restrict__ dvals, const float* __restrict__ bmin,
                      const float* __restrict__ bmax, float* __restrict__ out) {
    int b = blockIdx.x, t = threadIdx.x;
    __shared__ float smn, smx;
    if (t < 64) {
        float mn = bmin[b * SPLITS + t];
        float mx = bmax[b * SPLITS + t];
        #pragma unroll
        for (int off = 32; off > 0; off >>= 1) {
            mn = fminf(mn, __shfl_down(mn, off));
            mx = fmaxf(mx, __shfl_down(mx, off));
        }
        if (t == 0) { smn = mn; smx = mx; }
    }
    __syncthreads();
    float rmin = smn, inv = 1.f / (smx - smn);
    for (int i = t; i < HW; i += blockDim.x) {
        float d = dvals[b * HW + i];
        float rn = (d - rmin) * inv;
        float z = (rn - 0.65f) * (1.f / 0.15f);
        out[b * HW + i] = 1.f / (1.f + expf(-z));
    }
}

extern "C" void kernel_launch(void* const* d_in, const int* in_sizes, int n_in,
                              void* d_out, int out_size, void* d_ws, size_t ws_size,
                              hipStream_t stream) {
    const float* x      = (const float*)d_in[0];
    const float* conv_w = (const float*)d_in[1];
    const float* conv_b = (const float*)d_in[2];
    const float* q_w    = (const float*)d_in[3];
    // d_in[4] = q_b: adds a per-batch constant -> cancels in min-max norm
    const float* k_w    = (const float*)d_in[5];
    const float* k_b    = (const float*)d_in[6];
    float* out = (float*)d_out;

    float* ws    = (float*)d_ws;
    float* part  = ws;                              // 8*64*512 = 262144
    float* qwT   = part + BATCH * SPLITS * CH;      // 262144
    float* cwT   = qwT + CH * CH;                   // 262144
    float* y     = cwT + CH * CH;                   // 4096
    float* t1    = y  + BATCH * CH;                 // 4096
    float* t2    = t1 + BATCH * CH;                 // 4096
    float* w     = t2 + BATCH * CH;                 // 4096
    float* u     = w  + BATCH * CH;                 // 4096
    float* dvals = u  + BATCH * CH;                 // 8192
    float* bmn   = dvals + BATCH * HW;              // 512
    float* bmx   = bmn + BATCH * SPLITS;            // 512

    hipLaunchKernelGGL(k_transpose, dim3(64, 2),       dim3(256), 0, stream, q_w, conv_w, qwT, cwT);
    hipLaunchKernelGGL(k_xsum_part, dim3(SPLITS, BATCH), dim3(256), 0, stream, x, part);
    hipLaunchKernelGGL(k_ycompute,  dim3(8, BATCH),    dim3(256), 0, stream, part, y);
    hipLaunchKernelGGL(k_t1,        dim3(1024),        dim3(256), 0, stream, y, conv_w, conv_b, t1);
    hipLaunchKernelGGL(k_t2,        dim3(1024),        dim3(256), 0, stream, t1, k_w, k_b, t2);
    hipLaunchKernelGGL(k_wv,        dim3(1024),        dim3(256), 0, stream, t2, qwT, w);
    hipLaunchKernelGGL(k_uv,        dim3(1024),        dim3(256), 0, stream, w, cwT, u);
    hipLaunchKernelGGL(k_dpass,     dim3(SPLITS, BATCH), dim3(256), 0, stream, x, u, dvals, bmn, bmx);
    hipLaunchKernelGGL(k_out,       dim3(BATCH),       dim3(256), 0, stream, dvals, bmn, bmx, out);
}